// Round 9
// baseline (98.814 us; speedup 1.0000x reference)
//
#include <hip/hip_runtime.h>

#define HH 256
#define WW 512
#define NCIN 16
#define NCOUT 32
#define NB 4
#define KP 168     // Sl row stride in halfs (336 B)
#define WKP 168    // wtab row stride in halfs (pad zeroed through 167)
#define NPIX 64    // pixels per block

typedef _Float16 h2 __attribute__((ext_vector_type(2)));
typedef _Float16 half4 __attribute__((ext_vector_type(4)));
typedef _Float16 half8 __attribute__((ext_vector_type(8)));
typedef float f32x4 __attribute__((ext_vector_type(4)));

// ws layout
#define XT_OFF   0u                  // fp16 xt: 4*256*512*16 half = 16 MiB
#define XTAB_OFF 16777216u           // float2[256*9*512] = 9 MiB
#define WTAB_OFF (16777216u + 9437184u)          // half[32*168]
#define YTAB_OFF (16777216u + 9437184u + 16384u) // float4[256*9]
#define WS_NEED  (YTAB_OFF + 36864u)

// ---- precompute: fp16-transposed weights + per-(row,tap) y-side table ----
__global__ __launch_bounds__(256) void precompute_tabs(const float* __restrict__ w,
                                                       const float* __restrict__ grid,
                                                       _Float16* __restrict__ wtab,
                                                       float4* __restrict__ ytab) {
    const int t = blockIdx.x * 256 + threadIdx.x;
    if (t < NCOUT * WKP) {
        const int co = t / WKP, kk = t - co * WKP;
        float v = 0.0f;
        if (kk < 144) v = w[co * 144 + (kk & 15) * 9 + (kk >> 4)];
        wtab[t] = (_Float16)v;
    } else if (t < NCOUT * WKP + HH * 9) {
        const int u = t - NCOUT * WKP;
        const int r = u / 9, tap = u - r * 9;
        const int kr = tap / 3, kc = tap - kr * 3;
        const float2* g2 = reinterpret_cast<const float2*>(grid);
        const float gy = g2[(size_t)(r * 3 + kr) * (WW * 3) + kc].y;   // col 0 (gy col-indep)
        const float iy = ((gy + 1.0f) * 0.5f) * (float)(HH - 1);
        const float y0f = floorf(iy);
        const float fy = iy - y0f;
        const int y0 = (int)y0f, y1 = y0 + 1;
        float wy0 = 1.0f - fy, wy1 = fy;
        if (y0 < 0 || y0 > HH - 1) wy0 = 0.0f;
        if (y1 < 0 || y1 > HH - 1) wy1 = 0.0f;
        const int cy0 = min(max(y0, 0), HH - 1), cy1 = min(max(y1, 0), HH - 1);
        ytab[u] = make_float4(wy0, wy1, __int_as_float(cy0), __int_as_float(cy1));
    }
}

// ---- precompute: per-(row,tap,col) x-side {fx, x0} (always in-bounds by mod-W) ----
__global__ __launch_bounds__(256) void precompute_xtab(const float* __restrict__ grid,
                                                       float2* __restrict__ xtab) {
    const int t = blockIdx.x * 256 + threadIdx.x;   // (r*9+tap)*512 + c
    const int c = t & (WW - 1);
    const int u = t >> 9;
    const int r = u / 9, tap = u - r * 9;
    const int kr = tap / 3, kc = tap - kr * 3;
    const float2* g2 = reinterpret_cast<const float2*>(grid);
    const float gx = g2[(size_t)(r * 3 + kr) * (WW * 3) + (c * 3 + kc)].x;
    const float ix = ((gx + 1.0f) * 0.5f) * (float)(WW - 1);
    const float x0f = floorf(ix);
    xtab[t] = make_float2(ix - x0f, __int_as_float((int)x0f));
}

// ---- pre-pass: x (B,Cin,H,W) -> xh (B,H,W,Cin) fp16 ----
__global__ __launch_bounds__(256) void transpose_x_kernel(const float* __restrict__ x,
                                                          _Float16* __restrict__ xh) {
    const int lb = (blockIdx.x & 7) * 256 + (blockIdx.x >> 3);
    const int t = lb * 256 + threadIdx.x;
    const int c = t & (WW - 1);
    const int r = (t >> 9) & (HH - 1);
    const int b = t >> 17;
    const float* xp = x + ((size_t)(b * NCIN) * HH + r) * WW + c;
    half8 h0, h1;
#pragma unroll
    for (int ci = 0; ci < 8; ++ci)  h0[ci] = (_Float16)xp[(size_t)ci * (HH * WW)];
#pragma unroll
    for (int ci = 0; ci < 8; ++ci)  h1[ci] = (_Float16)xp[(size_t)(8 + ci) * (HH * WW)];
    half8* op = reinterpret_cast<half8*>(xh) + (size_t)t * 2;
    op[0] = h0;
    op[1] = h1;
}

// ---- fused sample+conv: table-driven S-build (pk-fp16 interp), reg-resident W ----
__global__ __launch_bounds__(256, 4) void sphere_mfma_kernel(const _Float16* __restrict__ xh,
                                                             const float2* __restrict__ xtab,
                                                             const _Float16* __restrict__ wtab,
                                                             const float4* __restrict__ ytab,
                                                             const float* __restrict__ bias,
                                                             float* __restrict__ out) {
    __shared__ _Float16 Sl[NPIX * KP];   // [p][kk], kk=tap*16+ci, pad 144..159 zeroed
    __shared__ float4 tab[9];            // {wy0, wy1, bitcast(R0), bitcast(R1)} half4-units
    const int tid = threadIdx.x, lane = tid & 63, wv = tid >> 6;
    const int col = lane & 15, g4 = lane >> 4;

    const int lb = ((blockIdx.x & 7) << 10) + (blockIdx.x >> 3);  // 8192 blocks, bijective
    const int pixbase = lb << 6;
    const int b    = pixbase >> 17;
    const int rimg = (pixbase >> 9) & (HH - 1);
    const int c0   = pixbase & (WW - 1);

    // W fragments -> registers (L2-hot wtab; zero-padded rows)
    half8 wA[5][2];
#pragma unroll
    for (int s = 0; s < 5; ++s)
#pragma unroll
        for (int m = 0; m < 2; ++m)
            wA[s][m] = *reinterpret_cast<const half8*>(wtab + (m * 16 + col) * WKP + s * 32 + g4 * 8);

    if (tid < 9) {
        const float4 y = ytab[rimg * 9 + tid];
        const int cy0 = __float_as_int(y.z), cy1 = __float_as_int(y.w);
        const int R0 = (b * HH + cy0) << 11;   // *(WW)*4 half4-units
        const int R1 = (b * HH + cy1) << 11;
        tab[tid] = make_float4(y.x, y.y, __int_as_float(R0), __int_as_float(R1));
    }
    if (tid < 128) {   // zero Sl pad kk 144..159
        const int p = tid >> 1, j = tid & 1;
        half8 z = {0, 0, 0, 0, 0, 0, 0, 0};
        *reinterpret_cast<half8*>(&Sl[p * KP + 144 + j * 8]) = z;
    }
    __syncthreads();

    // phase B: q-grouped S-build (lane = pl*4+q)
    const int pl = lane >> 2, q = lane & 3;
    const int p = wv * 16 + pl;
    const float2* xrow = xtab + (size_t)rimg * 9 * WW + (c0 + p);
    const half4* x4 = reinterpret_cast<const half4*>(xh);

#pragma unroll
    for (int tap = 0; tap < 9; ++tap) {
        const float2 f2 = xrow[tap * WW];
        const float fx = f2.x;
        const int x0 = __float_as_int(f2.y);
        const float4 tt = tab[tap];
        const float wx0 = 1.0f - fx;
        const float w00 = wx0 * tt.x, w01 = fx * tt.x, w10 = wx0 * tt.y, w11 = fx * tt.y;
        const h2 W00 = {(_Float16)w00, (_Float16)w00};
        const h2 W01 = {(_Float16)w01, (_Float16)w01};
        const h2 W10 = {(_Float16)w10, (_Float16)w10};
        const h2 W11 = {(_Float16)w11, (_Float16)w11};
        const int bq = (x0 << 2) + q;
        const int o00 = __float_as_int(tt.z) + bq;
        const int o10 = __float_as_int(tt.w) + bq;
        const half4 a00 = x4[o00], a01 = x4[o00 + 4];
        const half4 a10 = x4[o10], a11 = x4[o10 + 4];
        h2 lo = a00.lo * W00;
        lo += a01.lo * W01;
        lo += a10.lo * W10;
        lo += a11.lo * W11;
        h2 hi = a00.hi * W00;
        hi += a01.hi * W01;
        hi += a10.hi * W10;
        hi += a11.hi * W11;
        const half4 pk = {lo.x, lo.y, hi.x, hi.y};
        *reinterpret_cast<half4*>(&Sl[p * KP + tap * 16 + q * 4]) = pk;
    }
    __syncthreads();

    // MFMA: wave wv owns pixels [wv*16, wv*16+16), couts 0..31
    f32x4 acc0 = {0.f, 0.f, 0.f, 0.f}, acc1 = {0.f, 0.f, 0.f, 0.f};
#pragma unroll
    for (int s = 0; s < 5; ++s) {
        const half8 bf = *reinterpret_cast<const half8*>(&Sl[(wv * 16 + col) * KP + s * 32 + g4 * 8]);
        acc0 = __builtin_amdgcn_mfma_f32_16x16x32_f16(wA[s][0], bf, acc0, 0, 0, 0);
        acc1 = __builtin_amdgcn_mfma_f32_16x16x32_f16(wA[s][1], bf, acc1, 0, 0, 0);
    }

    // epilogue: C col=lane&15 (pixel), row=(lane>>4)*4+reg (cout)
    const int pix = c0 + wv * 16 + col;
    float* ob = out + (((size_t)(b * NCOUT) * HH + rimg) * WW) + pix;
#pragma unroll
    for (int m = 0; m < 2; ++m) {
        const f32x4 a = m ? acc1 : acc0;
#pragma unroll
        for (int r = 0; r < 4; ++r) {
            const int co = m * 16 + g4 * 4 + r;
            ob[(size_t)co * (HH * WW)] = a[r] + bias[co];
        }
    }
}

// Fallback (no workspace): round-1 direct-gather kernel (verified, ~146us).
__global__ __launch_bounds__(256) void sphere_conv_fallback(const float* __restrict__ x,
                                                            const float* __restrict__ weight,
                                                            const float* __restrict__ bias,
                                                            const float* __restrict__ grid,
                                                            float* __restrict__ out) {
    __shared__ float wlds[NCIN * 9 * NCOUT];
    const int tid = threadIdx.x;
    for (int e = tid; e < NCIN * 9 * NCOUT; e += 256) {
        const int co  = e & (NCOUT - 1);
        const int cik = e >> 5;
        wlds[e] = weight[co * (NCIN * 9) + cik];
    }
    __syncthreads();

    const int pindex = blockIdx.x * 256 + tid;
    const int c = pindex & (WW - 1);
    const int r = (pindex >> 9) & (HH - 1);
    const int b = pindex >> 17;

    float acc[NCOUT];
#pragma unroll
    for (int o = 0; o < NCOUT; ++o) acc[o] = 0.0f;

    const float2* g2 = reinterpret_cast<const float2*>(grid);

#pragma unroll 1
    for (int k = 0; k < 9; ++k) {
        const int kr = k / 3, kc = k - kr * 3;
        const float2 g = g2[(r * 3 + kr) * (WW * 3) + (c * 3 + kc)];
        const float ix = ((g.x + 1.0f) * 0.5f) * (float)(WW - 1);
        const float iy = ((g.y + 1.0f) * 0.5f) * (float)(HH - 1);
        const float x0f = floorf(ix), y0f = floorf(iy);
        const float fx = ix - x0f, fy = iy - y0f;
        const int x0 = (int)x0f, y0 = (int)y0f;
        const int x1 = x0 + 1, y1 = y0 + 1;
        float wx0 = 1.0f - fx, wx1 = fx, wy0 = 1.0f - fy, wy1 = fy;
        if (x0 < 0 || x0 > WW - 1) wx0 = 0.0f;
        if (x1 < 0 || x1 > WW - 1) wx1 = 0.0f;
        if (y0 < 0 || y0 > HH - 1) wy0 = 0.0f;
        if (y1 < 0 || y1 > HH - 1) wy1 = 0.0f;
        const int cx0 = min(max(x0, 0), WW - 1), cx1 = min(max(x1, 0), WW - 1);
        const int cy0 = min(max(y0, 0), HH - 1), cy1 = min(max(y1, 0), HH - 1);
        const float w00 = wx0 * wy0, w01 = wx1 * wy0, w10 = wx0 * wy1, w11 = wx1 * wy1;

#pragma unroll 1
        for (int ci = 0; ci < NCIN; ++ci) {
            const float* xb = x + (size_t)((b * NCIN + ci) * HH) * WW;
            const float a00 = xb[cy0 * WW + cx0];
            const float a01 = xb[cy0 * WW + cx1];
            const float a10 = xb[cy1 * WW + cx0];
            const float a11 = xb[cy1 * WW + cx1];
            const float s = w00 * a00 + w01 * a01 + w10 * a10 + w11 * a11;
            const float4* wl = reinterpret_cast<const float4*>(&wlds[(ci * 9 + k) * NCOUT]);
#pragma unroll
            for (int o = 0; o < 8; ++o) {
                const float4 wv = wl[o];
                acc[o * 4 + 0] += wv.x * s;
                acc[o * 4 + 1] += wv.y * s;
                acc[o * 4 + 2] += wv.z * s;
                acc[o * 4 + 3] += wv.w * s;
            }
        }
    }

    const int obase = ((b * NCOUT) * HH + r) * WW + c;
#pragma unroll
    for (int o = 0; o < NCOUT; ++o) {
        out[obase + o * (HH * WW)] = acc[o] + bias[o];
    }
}

extern "C" void kernel_launch(void* const* d_in, const int* in_sizes, int n_in,
                              void* d_out, int out_size, void* d_ws, size_t ws_size,
                              hipStream_t stream) {
    const float* x    = (const float*)d_in[0];
    const float* w    = (const float*)d_in[1];
    const float* bias = (const float*)d_in[2];
    const float* grid = (const float*)d_in[3];
    float* out = (float*)d_out;

    if (ws_size >= WS_NEED) {
        char* ws = (char*)d_ws;
        _Float16* xh   = (_Float16*)(ws + XT_OFF);
        float2*   xtab = (float2*)(ws + XTAB_OFF);
        _Float16* wtab = (_Float16*)(ws + WTAB_OFF);
        float4*   ytab = (float4*)(ws + YTAB_OFF);

        precompute_tabs<<<30, 256, 0, stream>>>(w, grid, wtab, ytab);
        precompute_xtab<<<4608, 256, 0, stream>>>(grid, xtab);
        transpose_x_kernel<<<2048, 256, 0, stream>>>(x, xh);
        sphere_mfma_kernel<<<8192, 256, 0, stream>>>(xh, xtab, wtab, ytab, bias, out);
    } else {
        sphere_conv_fallback<<<2048, 256, 0, stream>>>(x, w, bias, grid, out);
    }
}

// Round 10
// 85.865 us; speedup vs baseline: 1.1508x; 1.1508x over previous
//
#include <hip/hip_runtime.h>

#define HH 256
#define WW 512
#define NCIN 16
#define NCOUT 32
#define NB 4
#define KP 168     // Sl row stride in halfs (336 B)
#define WKP 168    // wtab row stride in halfs (pad zeroed through 167)
#define NPIX 64    // pixels per block

typedef _Float16 h2 __attribute__((ext_vector_type(2)));
typedef _Float16 half4 __attribute__((ext_vector_type(4)));
typedef _Float16 half8 __attribute__((ext_vector_type(8)));
typedef float f32x4 __attribute__((ext_vector_type(4)));

// ws layout
#define XT_OFF   0u                  // fp16 xt: 4*256*512*16 half = 16 MiB
#define XTAB_OFF 16777216u           // float2[256*9*512] = 9 MiB
#define WTAB_OFF (16777216u + 9437184u)          // half[32*168]
#define YTAB_OFF (16777216u + 9437184u + 16384u) // float4[256*9]
#define WS_NEED  (YTAB_OFF + 36864u)

// ---- precompute (merged): xtab (blocks 0..4607), wtab+ytab (blocks 4608..4637) ----
__global__ __launch_bounds__(256) void precompute_all(const float* __restrict__ w,
                                                      const float* __restrict__ grid,
                                                      float2* __restrict__ xtab,
                                                      _Float16* __restrict__ wtab,
                                                      float4* __restrict__ ytab) {
    const float2* g2 = reinterpret_cast<const float2*>(grid);
    if (blockIdx.x < 4608) {
        const int t = blockIdx.x * 256 + threadIdx.x;   // (r*9+tap)*512 + c
        const int c = t & (WW - 1);
        const int u = t >> 9;
        const int r = u / 9, tap = u - r * 9;
        const int kr = tap / 3, kc = tap - kr * 3;
        const float gx = g2[(size_t)(r * 3 + kr) * (WW * 3) + (c * 3 + kc)].x;
        const float ix = ((gx + 1.0f) * 0.5f) * (float)(WW - 1);
        const float x0f = floorf(ix);
        xtab[t] = make_float2(ix - x0f, __int_as_float((int)x0f));
        return;
    }
    const int t = (blockIdx.x - 4608) * 256 + threadIdx.x;
    if (t < NCOUT * WKP) {
        const int co = t / WKP, kk = t - co * WKP;
        float v = 0.0f;
        if (kk < 144) v = w[co * 144 + (kk & 15) * 9 + (kk >> 4)];
        wtab[t] = (_Float16)v;
    } else if (t < NCOUT * WKP + HH * 9) {
        const int u = t - NCOUT * WKP;
        const int r = u / 9, tap = u - r * 9;
        const int kr = tap / 3, kc = tap - kr * 3;
        const float gy = g2[(size_t)(r * 3 + kr) * (WW * 3) + kc].y;   // col 0 (gy col-indep)
        const float iy = ((gy + 1.0f) * 0.5f) * (float)(HH - 1);
        const float y0f = floorf(iy);
        const float fy = iy - y0f;
        const int y0 = (int)y0f, y1 = y0 + 1;
        float wy0 = 1.0f - fy, wy1 = fy;
        if (y0 < 0 || y0 > HH - 1) wy0 = 0.0f;
        if (y1 < 0 || y1 > HH - 1) wy1 = 0.0f;
        const int cy0 = min(max(y0, 0), HH - 1), cy1 = min(max(y1, 0), HH - 1);
        ytab[u] = make_float4(wy0, wy1, __int_as_float(cy0), __int_as_float(cy1));
    }
}

// ---- pre-pass: x (B,Cin,H,W) -> xh (B,H,W,Cin) fp16 ----
__global__ __launch_bounds__(256) void transpose_x_kernel(const float* __restrict__ x,
                                                          _Float16* __restrict__ xh) {
    const int lb = (blockIdx.x & 7) * 256 + (blockIdx.x >> 3);
    const int t = lb * 256 + threadIdx.x;
    const int c = t & (WW - 1);
    const int r = (t >> 9) & (HH - 1);
    const int b = t >> 17;
    const float* xp = x + ((size_t)(b * NCIN) * HH + r) * WW + c;
    half8 h0, h1;
#pragma unroll
    for (int ci = 0; ci < 8; ++ci)  h0[ci] = (_Float16)xp[(size_t)ci * (HH * WW)];
#pragma unroll
    for (int ci = 0; ci < 8; ++ci)  h1[ci] = (_Float16)xp[(size_t)(8 + ci) * (HH * WW)];
    half8* op = reinterpret_cast<half8*>(xh) + (size_t)t * 2;
    op[0] = h0;
    op[1] = h1;
}

// ---- fused sample+conv. Round-10: FULL load hoist for MLP — all 9 xtab loads,
// then all 36 gathers issued before any interp consumes them (r8=r9=78us at
// VGPR 36-60 diagnosed as exposed-latency serialization, not pipe throughput).
__global__ __launch_bounds__(256, 3) void sphere_mfma_kernel(const _Float16* __restrict__ xh,
                                                             const float2* __restrict__ xtab,
                                                             const _Float16* __restrict__ wtab,
                                                             const float4* __restrict__ ytab,
                                                             const float* __restrict__ bias,
                                                             float* __restrict__ out) {
    __shared__ _Float16 Sl[NPIX * KP];   // [p][kk], kk=tap*16+ci, pad 144..159 zeroed
    const int tid = threadIdx.x, lane = tid & 63, wv = tid >> 6;
    const int col = lane & 15, g4 = lane >> 4;

    const int lb = ((blockIdx.x & 7) << 10) + (blockIdx.x >> 3);  // 8192 blocks, bijective
    const int pixbase = lb << 6;
    const int b    = pixbase >> 17;
    const int rimg = (pixbase >> 9) & (HH - 1);
    const int c0   = pixbase & (WW - 1);

    const int pl = lane >> 2, q = lane & 3;
    const int p  = wv * 16 + pl;

    if (tid < 128) {   // zero Sl pad kk 144..159
        const int pp = tid >> 1, j = tid & 1;
        half8 z = {0, 0, 0, 0, 0, 0, 0, 0};
        *reinterpret_cast<half8*>(&Sl[pp * KP + 144 + j * 8]) = z;
    }

    // ---- issue ALL 9 x-side table loads ----
    const float2* xrow = xtab + (size_t)rimg * 9 * WW + (c0 + p);
    float2 f2s[9];
#pragma unroll
    for (int t = 0; t < 9; ++t) f2s[t] = xrow[t * WW];

    // ---- wave-uniform y-side data (scalar loads) ----
    float wy0s[9], wy1s[9];
    int Rb0[9], Rb1[9];
#pragma unroll
    for (int t = 0; t < 9; ++t) {
        const float4 y = ytab[rimg * 9 + t];
        wy0s[t] = y.x;
        wy1s[t] = y.y;
        Rb0[t] = (b * HH + __float_as_int(y.z)) << 11;   // half4-unit row base
        Rb1[t] = (b * HH + __float_as_int(y.w)) << 11;
    }

    // ---- issue ALL 36 gathers (36 loads in flight per lane) ----
    const half4* x4 = reinterpret_cast<const half4*>(xh);
    half4 A00[9], A01[9], A10[9], A11[9];
#pragma unroll
    for (int t = 0; t < 9; ++t) {
        const int bq = (__float_as_int(f2s[t].y) << 2) + q;
        const int o0 = Rb0[t] + bq, o1 = Rb1[t] + bq;
        A00[t] = x4[o0];
        A01[t] = x4[o0 + 4];
        A10[t] = x4[o1];
        A11[t] = x4[o1 + 4];
    }

    // ---- interp (pk-fp16, identical arithmetic/order to round 9) + Sl writes ----
#pragma unroll
    for (int t = 0; t < 9; ++t) {
        const float fx = f2s[t].x;
        const float wx0 = 1.0f - fx;
        const float w00 = wx0 * wy0s[t], w01 = fx * wy0s[t];
        const float w10 = wx0 * wy1s[t], w11 = fx * wy1s[t];
        const h2 W00 = {(_Float16)w00, (_Float16)w00};
        const h2 W01 = {(_Float16)w01, (_Float16)w01};
        const h2 W10 = {(_Float16)w10, (_Float16)w10};
        const h2 W11 = {(_Float16)w11, (_Float16)w11};
        h2 lo = A00[t].lo * W00;
        lo += A01[t].lo * W01;
        lo += A10[t].lo * W10;
        lo += A11[t].lo * W11;
        h2 hi = A00[t].hi * W00;
        hi += A01[t].hi * W01;
        hi += A10[t].hi * W10;
        hi += A11[t].hi * W11;
        const half4 pk = {lo.x, lo.y, hi.x, hi.y};
        *reinterpret_cast<half4*>(&Sl[p * KP + t * 16 + q * 4]) = pk;
    }

    // ---- W fragments -> registers (after interp: lifetimes don't overlap A[]) ----
    half8 wA[5][2];
#pragma unroll
    for (int s = 0; s < 5; ++s)
#pragma unroll
        for (int m = 0; m < 2; ++m)
            wA[s][m] = *reinterpret_cast<const half8*>(wtab + (m * 16 + col) * WKP + s * 32 + g4 * 8);

    __syncthreads();

    // ---- MFMA: wave wv owns pixels [wv*16, wv*16+16), couts 0..31 ----
    f32x4 acc0 = {0.f, 0.f, 0.f, 0.f}, acc1 = {0.f, 0.f, 0.f, 0.f};
#pragma unroll
    for (int s = 0; s < 5; ++s) {
        const half8 bf = *reinterpret_cast<const half8*>(&Sl[(wv * 16 + col) * KP + s * 32 + g4 * 8]);
        acc0 = __builtin_amdgcn_mfma_f32_16x16x32_f16(wA[s][0], bf, acc0, 0, 0, 0);
        acc1 = __builtin_amdgcn_mfma_f32_16x16x32_f16(wA[s][1], bf, acc1, 0, 0, 0);
    }

    // ---- epilogue: C col=lane&15 (pixel), row=(lane>>4)*4+reg (cout) ----
    const int pix = c0 + wv * 16 + col;
    float* ob = out + (((size_t)(b * NCOUT) * HH + rimg) * WW) + pix;
#pragma unroll
    for (int m = 0; m < 2; ++m) {
        const f32x4 a = m ? acc1 : acc0;
#pragma unroll
        for (int r = 0; r < 4; ++r) {
            const int co = m * 16 + g4 * 4 + r;
            ob[(size_t)co * (HH * WW)] = a[r] + bias[co];
        }
    }
}

// Fallback (no workspace): round-1 direct-gather kernel (verified, ~146us).
__global__ __launch_bounds__(256) void sphere_conv_fallback(const float* __restrict__ x,
                                                            const float* __restrict__ weight,
                                                            const float* __restrict__ bias,
                                                            const float* __restrict__ grid,
                                                            float* __restrict__ out) {
    __shared__ float wlds[NCIN * 9 * NCOUT];
    const int tid = threadIdx.x;
    for (int e = tid; e < NCIN * 9 * NCOUT; e += 256) {
        const int co  = e & (NCOUT - 1);
        const int cik = e >> 5;
        wlds[e] = weight[co * (NCIN * 9) + cik];
    }
    __syncthreads();

    const int pindex = blockIdx.x * 256 + tid;
    const int c = pindex & (WW - 1);
    const int r = (pindex >> 9) & (HH - 1);
    const int b = pindex >> 17;

    float acc[NCOUT];
#pragma unroll
    for (int o = 0; o < NCOUT; ++o) acc[o] = 0.0f;

    const float2* g2 = reinterpret_cast<const float2*>(grid);

#pragma unroll 1
    for (int k = 0; k < 9; ++k) {
        const int kr = k / 3, kc = k - kr * 3;
        const float2 g = g2[(r * 3 + kr) * (WW * 3) + (c * 3 + kc)];
        const float ix = ((g.x + 1.0f) * 0.5f) * (float)(WW - 1);
        const float iy = ((g.y + 1.0f) * 0.5f) * (float)(HH - 1);
        const float x0f = floorf(ix), y0f = floorf(iy);
        const float fx = ix - x0f, fy = iy - y0f;
        const int x0 = (int)x0f, y0 = (int)y0f;
        const int x1 = x0 + 1, y1 = y0 + 1;
        float wx0 = 1.0f - fx, wx1 = fx, wy0 = 1.0f - fy, wy1 = fy;
        if (x0 < 0 || x0 > WW - 1) wx0 = 0.0f;
        if (x1 < 0 || x1 > WW - 1) wx1 = 0.0f;
        if (y0 < 0 || y0 > HH - 1) wy0 = 0.0f;
        if (y1 < 0 || y1 > HH - 1) wy1 = 0.0f;
        const int cx0 = min(max(x0, 0), WW - 1), cx1 = min(max(x1, 0), WW - 1);
        const int cy0 = min(max(y0, 0), HH - 1), cy1 = min(max(y1, 0), HH - 1);
        const float w00 = wx0 * wy0, w01 = wx1 * wy0, w10 = wx0 * wy1, w11 = wx1 * wy1;

#pragma unroll 1
        for (int ci = 0; ci < NCIN; ++ci) {
            const float* xb = x + (size_t)((b * NCIN + ci) * HH) * WW;
            const float a00 = xb[cy0 * WW + cx0];
            const float a01 = xb[cy0 * WW + cx1];
            const float a10 = xb[cy1 * WW + cx0];
            const float a11 = xb[cy1 * WW + cx1];
            const float s = w00 * a00 + w01 * a01 + w10 * a10 + w11 * a11;
            const float4* wl = reinterpret_cast<const float4*>(&wlds[(ci * 9 + k) * NCOUT]);
#pragma unroll
            for (int o = 0; o < 8; ++o) {
                const float4 wv = wl[o];
                acc[o * 4 + 0] += wv.x * s;
                acc[o * 4 + 1] += wv.y * s;
                acc[o * 4 + 2] += wv.z * s;
                acc[o * 4 + 3] += wv.w * s;
            }
        }
    }

    const int obase = ((b * NCOUT) * HH + r) * WW + c;
#pragma unroll
    for (int o = 0; o < NCOUT; ++o) {
        out[obase + o * (HH * WW)] = acc[o] + bias[o];
    }
}

extern "C" void kernel_launch(void* const* d_in, const int* in_sizes, int n_in,
                              void* d_out, int out_size, void* d_ws, size_t ws_size,
                              hipStream_t stream) {
    const float* x    = (const float*)d_in[0];
    const float* w    = (const float*)d_in[1];
    const float* bias = (const float*)d_in[2];
    const float* grid = (const float*)d_in[3];
    float* out = (float*)d_out;

    if (ws_size >= WS_NEED) {
        char* ws = (char*)d_ws;
        _Float16* xh   = (_Float16*)(ws + XT_OFF);
        float2*   xtab = (float2*)(ws + XTAB_OFF);
        _Float16* wtab = (_Float16*)(ws + WTAB_OFF);
        float4*   ytab = (float4*)(ws + YTAB_OFF);

        precompute_all<<<4638, 256, 0, stream>>>(w, grid, xtab, wtab, ytab);
        transpose_x_kernel<<<2048, 256, 0, stream>>>(x, xh);
        sphere_mfma_kernel<<<8192, 256, 0, stream>>>(xh, xtab, wtab, ytab, bias, out);
    } else {
        sphere_conv_fallback<<<2048, 256, 0, stream>>>(x, w, bias, grid, out);
    }
}